// Round 7
// baseline (5248.667 us; speedup 1.0000x reference)
//
#include <hip/hip_runtime.h>
#include <hip/hip_bf16.h>

// GatedLSTM: B=64, T=256, IN=512, H=1024. i-gate dead -> dropped.
// Round 7: BATCH-GROUP SOFTWARE PIPELINE. The 64 batch rows are independent
// recurrences; split into 4 groups of 16. Slot s=(t,g)=(s>>2,s&3). Each wave
// owns 2 h-cols x full K=1024 (M=16,N=16: cols = 6 U-mats x 2 + 4 pad) ->
// no cross-wave reduce, NO __syncthreads in the loop. Exchange latency for
// group g hides under 3 other groups' compute: af loads issued 1 slot ahead,
// poll flags 2 slots ahead, h-store ack folded into next slot's natural
// vmcnt(0). B-frags + A-frags live in registers (1 wave/SIMD, 512 VGPR).

typedef __attribute__((ext_vector_type(8))) short bfrag;   // 8 x bf16
typedef __attribute__((ext_vector_type(4))) float f32x4;   // MFMA acc

__device__ __forceinline__ unsigned short f2b(float v) {
  __hip_bfloat16 h = __float2bfloat16(v);
  union { __hip_bfloat16 h; unsigned short u; } c; c.h = h; return c.u;
}
__device__ __forceinline__ float b2f(unsigned short u) {
  union { unsigned int i; float f; } c; c.i = ((unsigned int)u) << 16; return c.f;
}
__device__ __forceinline__ float sigm(float x) { return 1.0f / (1.0f + __expf(-x)); }
__device__ __forceinline__ float tanh_f(float x) {
  float e = __expf(2.0f * x);
  return (e - 1.0f) / (e + 1.0f);
}

// ---------------------------------------------------------------------------
// Phase 1: x-projections (unchanged, proven). mlx[t][g][j][b] bf16.
// ---------------------------------------------------------------------------
__global__ __launch_bounds__(512, 2) void xproj_kernel(
    const float* __restrict__ inp,
    const float* __restrict__ Wf, const float* __restrict__ Wmf,
    const float* __restrict__ Wo, const float* __restrict__ Wmo,
    const float* __restrict__ Wc, const float* __restrict__ Wmc,
    unsigned short* __restrict__ mlx)
{
  __shared__ unsigned short Al[256 * 128];
  __shared__ unsigned short Bl[256 * 128];

  const int tid = threadIdx.x;
  const int w = tid >> 6, l = tid & 63;
  const int c = l & 15, g4 = l >> 4;
  const int jc = blockIdx.x, gate = blockIdx.y, tq = blockIdx.z;
  const float* W  = (gate == 0) ? Wf  : (gate == 1) ? Wo  : Wc;
  const float* Wm = (gate == 0) ? Wmf : (gate == 1) ? Wmo : Wmc;
  const int j0 = jc * 128;

  f32x4 acc[2][16];
#pragma unroll
  for (int mi = 0; mi < 2; ++mi)
#pragma unroll
    for (int ni = 0; ni < 16; ++ni) acc[mi][ni] = (f32x4){0.f, 0.f, 0.f, 0.f};

  for (int kc = 0; kc < 4; ++kc) {
#pragma unroll
    for (int i = 0; i < 16; ++i) {
      int idx = tid + i * 512;
      int row = idx >> 5;
      int xl  = idx & 31;
      int b_ = row & 63, tl = row >> 6;
      const float4 va = *(const float4*)(inp + (size_t)(b_ * 256 + tq * 4 + tl) * 512 + kc * 128 + xl * 4);
      ushort4 pa;
      pa.x = f2b(va.x); pa.y = f2b(va.y); pa.z = f2b(va.z); pa.w = f2b(va.w);
      *(ushort4*)((char*)Al + ((row * 256 + xl * 8) ^ ((row & 7) << 4))) = pa;
      const float* src = (row < 128) ? (W + (size_t)(j0 + row) * 512)
                                     : (Wm + (size_t)(j0 + row - 128) * 512);
      const float4 vb = *(const float4*)(src + kc * 128 + xl * 4);
      ushort4 pb;
      pb.x = f2b(vb.x); pb.y = f2b(vb.y); pb.z = f2b(vb.z); pb.w = f2b(vb.w);
      *(ushort4*)((char*)Bl + ((row * 256 + xl * 8) ^ ((row & 7) << 4))) = pb;
    }
    __syncthreads();
#pragma unroll
    for (int ks = 0; ks < 4; ++ks) {
      const int koff = (ks * 32 + g4 * 8) * 2;
      bfrag af[2];
#pragma unroll
      for (int mi = 0; mi < 2; ++mi) {
        int row = w * 32 + mi * 16 + c;
        af[mi] = *(const bfrag*)((const char*)Al + ((row * 256 + koff) ^ ((row & 7) << 4)));
      }
#pragma unroll
      for (int ni = 0; ni < 16; ++ni) {
        int n = ni * 16 + c;
        bfrag bf = *(const bfrag*)((const char*)Bl + ((n * 256 + koff) ^ ((n & 7) << 4)));
#pragma unroll
        for (int mi = 0; mi < 2; ++mi)
          acc[mi][ni] = __builtin_amdgcn_mfma_f32_16x16x32_bf16(af[mi], bf, acc[mi][ni], 0, 0, 0);
      }
    }
    __syncthreads();
  }
#pragma unroll
  for (int mi = 0; mi < 2; ++mi) {
#pragma unroll
    for (int ni = 0; ni < 8; ++ni) {
      f32x4 xw = acc[mi][ni];
      f32x4 xm = acc[mi][ni + 8];
      ushort4 st;
      st.x = f2b(xw[0] * sigm(xm[0]));
      st.y = f2b(xw[1] * sigm(xm[1]));
      st.z = f2b(xw[2] * sigm(xm[2]));
      st.w = f2b(xw[3] * sigm(xm[3]));
      int row = w * 32 + mi * 16 + g4 * 4;
      int tl = row >> 6, b_ = row & 63;
      int j = j0 + ni * 16 + c;
      size_t addr = ((size_t)((tq * 4 + tl) * 3 + gate) * 1024 + j) * 64 + b_;
      *(ushort4*)(mlx + addr) = st;
    }
  }
}

// ---------------------------------------------------------------------------
// Phase 2: pipelined recurrent kernel. 128 blocks x 256 thr, 1 block/CU.
// Wave W = bid*4+w owns h-cols {2W, 2W+1}. hx regions: region(rho) holds
// h[rho>>2][g=rho&3][r:16][k:1024] bf16 (32 KB each); region rho written by
// h-stores at slot rho-3, sentinel sent[rho][W] set at slot rho-2, consumer
// poll-loads issued at slot rho-2, checked rho-1, data loaded rho-1, MFMA rho.
// ---------------------------------------------------------------------------
__global__ __launch_bounds__(256, 1) void recur_kernel(
    const float* __restrict__ Uf, const float* __restrict__ Umf,
    const float* __restrict__ Uo, const float* __restrict__ Umo,
    const float* __restrict__ Uc, const float* __restrict__ Umc,
    const float* __restrict__ bfp, const float* __restrict__ bop,
    const float* __restrict__ bcp,
    const unsigned short* __restrict__ mlx,  // [256][3][1024][64] bf16
    unsigned short* __restrict__ hx,         // [1028][16][1024] bf16
    float* __restrict__ cfin,                // [1024][64] f32
    unsigned int* __restrict__ sent)         // [1028][512]
{
  __shared__ float ldsT[4][16][17];          // per-wave C transpose (4.3 KB)

  __builtin_amdgcn_fence(__ATOMIC_ACQUIRE, "agent");  // cross-replay inval

  const int tid = threadIdx.x;
  const int bid = blockIdx.x;
  const int w = tid >> 6, l = tid & 63;
  const int c = l & 15, g4 = l >> 4;
  const int W = bid * 4 + w;                 // global wave 0..511
  const int r = c;                           // batch row within group
  const int q = g4 & 1;                      // h-col parity for gates

  // ---- one-time B stage into regs: col c -> (m=c>>1, q2=c&1), row j=2W+q2
  bfrag Breg[32];
  {
    const int m = c >> 1, q2 = c & 1;
    const float* up = (m == 0) ? Uf : (m == 1) ? Umf : (m == 2) ? Uo
                    : (m == 3) ? Umo : (m == 4) ? Uc : Umc;
    const float* src = up + (size_t)(2 * W + q2) * 1024;
    const bool pad = (c >= 12);
#pragma unroll
    for (int kc = 0; kc < 32; ++kc) {
      bfrag b = {0, 0, 0, 0, 0, 0, 0, 0};
      if (!pad) {
        const float4 v0 = *(const float4*)(src + kc * 32 + g4 * 8);
        const float4 v1 = *(const float4*)(src + kc * 32 + g4 * 8 + 4);
        b[0] = (short)f2b(v0.x); b[1] = (short)f2b(v0.y);
        b[2] = (short)f2b(v0.z); b[3] = (short)f2b(v0.w);
        b[4] = (short)f2b(v1.x); b[5] = (short)f2b(v1.y);
        b[6] = (short)f2b(v1.z); b[7] = (short)f2b(v1.w);
      }
      Breg[kc] = b;
    }
  }
  const float bf_ = bfp[2 * W + q], bo_ = bop[2 * W + q], bc_ = bcp[2 * W + q];

  bfrag af[32];                               // A-frags, 1-slot prefetch
  f32x4 accA = {0.f,0.f,0.f,0.f}, accB = {0.f,0.f,0.f,0.f};
  float crA = 0.f, crB = 0.f, crC = 0.f, crD = 0.f;
  unsigned long long P0[4] = {0,0,0,0}, P1[4] = {0,0,0,0};
  float mA0=0.f,mA1=0.f,mA2=0.f, mB0=0.f,mB1=0.f,mB2=0.f;
  const unsigned long long SOK = 0x0000000100000001ULL;

#define SLOT(Pp, ACCP, ACCC, CR, MI0, MI1, MI2, MO0, MO1, MO2, PCHK, PNEW)     \
  do {                                                                         \
    const int s_ = t4 * 4 + (Pp);                                              \
    /* K-loop on prefetched af -> ACCC (4 interleaved MFMA chains) */          \
    if (t4 > 0) {                                                              \
      f32x4 c0={0.f,0.f,0.f,0.f}, c1={0.f,0.f,0.f,0.f};                        \
      f32x4 c2={0.f,0.f,0.f,0.f}, c3={0.f,0.f,0.f,0.f};                        \
      _Pragma("unroll")                                                        \
      for (int kc = 0; kc < 32; kc += 4) {                                     \
        c0 = __builtin_amdgcn_mfma_f32_16x16x32_bf16(af[kc+0], Breg[kc+0], c0, 0,0,0); \
        c1 = __builtin_amdgcn_mfma_f32_16x16x32_bf16(af[kc+1], Breg[kc+1], c1, 0,0,0); \
        c2 = __builtin_amdgcn_mfma_f32_16x16x32_bf16(af[kc+2], Breg[kc+2], c2, 0,0,0); \
        c3 = __builtin_amdgcn_mfma_f32_16x16x32_bf16(af[kc+3], Breg[kc+3], c3, 0,0,0); \
      }                                                                        \
      ACCC = (c0 + c1) + (c2 + c3);                                            \
    } else {                                                                   \
      ACCC = (f32x4){0.f, 0.f, 0.f, 0.f};                                      \
    }                                                                          \
    /* drain (h-store(s-1), P, mlx all long since issued) then sentinel */     \
    asm volatile("s_waitcnt vmcnt(0)" ::: "memory");                           \
    if (s_ >= 2 && l == 0)                                                     \
      __hip_atomic_store(&sent[(size_t)(s_ + 2) * 512 + W], 1u,                \
                         __ATOMIC_RELAXED, __HIP_MEMORY_SCOPE_AGENT);          \
    /* poll-check for slot s+1, then issue its 32 A-frag loads (cached) */     \
    if ((s_ + 1) >= 4 && (s_ + 1) <= 1023) {                                   \
      while (true) {                                                           \
        bool ok = (PCHK[0] == SOK) && (PCHK[1] == SOK) &&                      \
                  (PCHK[2] == SOK) && (PCHK[3] == SOK);                        \
        if (__all(ok)) break;                                                  \
        const unsigned long long* pp =                                         \
            (const unsigned long long*)(sent + (size_t)(s_ + 1) * 512) + 4*l;  \
        PCHK[0] = __hip_atomic_load(pp+0, __ATOMIC_RELAXED, __HIP_MEMORY_SCOPE_AGENT); \
        PCHK[1] = __hip_atomic_load(pp+1, __ATOMIC_RELAXED, __HIP_MEMORY_SCOPE_AGENT); \
        PCHK[2] = __hip_atomic_load(pp+2, __ATOMIC_RELAXED, __HIP_MEMORY_SCOPE_AGENT); \
        PCHK[3] = __hip_atomic_load(pp+3, __ATOMIC_RELAXED, __HIP_MEMORY_SCOPE_AGENT); \
      }                                                                        \
      __builtin_amdgcn_sched_barrier(0);                                       \
      asm volatile("" ::: "memory");                                           \
      const unsigned short* ap = hx + (size_t)(s_ + 1) * 16384 + c * 1024 + g4 * 8; \
      _Pragma("unroll")                                                        \
      for (int kc = 0; kc < 32; ++kc) af[kc] = *(const bfrag*)(ap + kc * 32);  \
    }                                                                          \
    /* gates for logical slot s-1 (ACCP), publish h into region s_+3 */        \
    if (s_ >= 1) {                                                             \
      const int tl = ((Pp) >= 1) ? t4 : (t4 - 1);                              \
      const int gl = ((Pp) + 3) & 3;                                           \
      ldsT[w][g4 * 4 + 0][c] = ACCP[0];                                        \
      ldsT[w][g4 * 4 + 1][c] = ACCP[1];                                        \
      ldsT[w][g4 * 4 + 2][c] = ACCP[2];                                        \
      ldsT[w][g4 * 4 + 3][c] = ACCP[3];                                        \
      float s0 = ldsT[w][r][0 + q], s1 = ldsT[w][r][2 + q];                    \
      float s2 = ldsT[w][r][4 + q], s3 = ldsT[w][r][6 + q];                    \
      float s4 = ldsT[w][r][8 + q], s5 = ldsT[w][r][10 + q];                   \
      float fg = sigm((MI0) + sigm(s1) * s0 + bf_);                            \
      float og = sigm((MI1) + sigm(s3) * s2 + bo_);                            \
      float cd = tanh_f((MI2) + sigm(s5) * s4 + bc_);                          \
      CR = fg * CR + cd;                                                       \
      float hv = og * CR;                                                      \
      unsigned int hvu = f2b(hv);                                              \
      unsigned int hi = (unsigned int)__shfl((int)hvu, (l + 16) & 63, 64);     \
      unsigned int pack = (hvu & 0xFFFFu) | (hi << 16);                        \
      if (l < 16)                                                              \
        __hip_atomic_store(                                                    \
            (unsigned int*)(hx + (size_t)(s_ + 3) * 16384 + l * 1024 + 2 * W), \
            pack, __ATOMIC_RELAXED, __HIP_MEMORY_SCOPE_AGENT);                 \
      if (tl == 255 && l < 32)                                                 \
        cfin[(size_t)(2 * W + q) * 64 + gl * 16 + r] = CR;                     \
    }                                                                          \
    /* issue poll-loads for slot s+2 */                                        \
    if ((s_ + 2) >= 4 && (s_ + 2) <= 1023) {                                   \
      const unsigned long long* pp =                                           \
          (const unsigned long long*)(sent + (size_t)(s_ + 2) * 512) + 4 * l;  \
      PNEW[0] = __hip_atomic_load(pp+0, __ATOMIC_RELAXED, __HIP_MEMORY_SCOPE_AGENT); \
      PNEW[1] = __hip_atomic_load(pp+1, __ATOMIC_RELAXED, __HIP_MEMORY_SCOPE_AGENT); \
      PNEW[2] = __hip_atomic_load(pp+2, __ATOMIC_RELAXED, __HIP_MEMORY_SCOPE_AGENT); \
      PNEW[3] = __hip_atomic_load(pp+3, __ATOMIC_RELAXED, __HIP_MEMORY_SCOPE_AGENT); \
    }                                                                          \
    /* prefetch mlx for logical slot s (used by gates next slot) */            \
    if (s_ <= 1023) {                                                          \
      size_t mb = ((size_t)t4 * 3 * 1024 + (2 * W + q)) * 64 + (Pp) * 16 + r;  \
      MO0 = b2f(mlx[mb]);                                                      \
      MO1 = b2f(mlx[mb + 65536]);                                              \
      MO2 = b2f(mlx[mb + 131072]);                                             \
    }                                                                          \
  } while (0)

#pragma unroll 1
  for (int t4 = 0; t4 < 256; ++t4) {
    SLOT(0, accB, accA, crD, mB0, mB1, mB2, mA0, mA1, mA2, P1, P0);
    SLOT(1, accA, accB, crA, mA0, mA1, mA2, mB0, mB1, mB2, P0, P1);
    SLOT(2, accB, accA, crB, mB0, mB1, mB2, mA0, mA1, mA2, P1, P0);
    SLOT(3, accA, accB, crC, mA0, mA1, mA2, mB0, mB1, mB2, P0, P1);
  }
  // epilogue slot s=1024: gates for logical 1023 (t=255, g=3); K/poll/mlx
  // self-disable via guards (K output unused).
  {
    const int t4 = 256;
    SLOT(0, accB, accA, crD, mB0, mB1, mB2, mA0, mA1, mA2, P1, P0);
  }
#undef SLOT
}

// ---------------------------------------------------------------------------
// Phase 3: hx regions -> out [b][t][j] f32 (streaming cast)
// ---------------------------------------------------------------------------
__global__ __launch_bounds__(128) void histcast_kernel(
    const unsigned short* __restrict__ hx, float* __restrict__ out)
{
  const int b = blockIdx.x >> 8, t = blockIdx.x & 255;
  const int j = threadIdx.x * 8;
  const unsigned short* src =
      hx + (size_t)((t + 1) * 4 + (b >> 4)) * 16384 + (b & 15) * 1024 + j;
  float* dst = out + ((size_t)b * 256 + t) * 1024 + j;
  ushort4 v0 = *(const ushort4*)(src);
  ushort4 v1 = *(const ushort4*)(src + 4);
  float4 o0, o1;
  o0.x = b2f(v0.x); o0.y = b2f(v0.y); o0.z = b2f(v0.z); o0.w = b2f(v0.w);
  o1.x = b2f(v1.x); o1.y = b2f(v1.y); o1.z = b2f(v1.z); o1.w = b2f(v1.w);
  *(float4*)(dst) = o0;
  *(float4*)(dst + 4) = o1;
}

__global__ __launch_bounds__(256) void finals_kernel(
    const unsigned short* __restrict__ hx, const float* __restrict__ cfin,
    float* __restrict__ out)
{
  int tid = blockIdx.x * 256 + threadIdx.x;  // 0..65535 = b*1024 + j
  int b = tid >> 10, j = tid & 1023;
  out[16777216 + tid] =
      b2f(hx[(size_t)(1024 + (b >> 4)) * 16384 + (b & 15) * 1024 + j]);
  out[16777216 + 65536 + tid] = cfin[(size_t)j * 64 + b];
}

// ---------------------------------------------------------------------------
extern "C" void kernel_launch(void* const* d_in, const int* in_sizes, int n_in,
                              void* d_out, int out_size, void* d_ws, size_t ws_size,
                              hipStream_t stream)
{
  const float* input = (const float*)d_in[0];
  const float* W_f  = (const float*)d_in[1];
  const float* Wm_f = (const float*)d_in[2];
  const float* U_f  = (const float*)d_in[3];
  const float* Um_f = (const float*)d_in[4];
  const float* b_f  = (const float*)d_in[5];
  const float* W_o  = (const float*)d_in[11];
  const float* Wm_o = (const float*)d_in[12];
  const float* U_o  = (const float*)d_in[13];
  const float* Um_o = (const float*)d_in[14];
  const float* b_o  = (const float*)d_in[15];
  const float* W_c  = (const float*)d_in[16];
  const float* Wm_c = (const float*)d_in[17];
  const float* U_c  = (const float*)d_in[18];
  const float* Um_c = (const float*)d_in[19];
  const float* b_c  = (const float*)d_in[20];

  char* ws = (char*)d_ws;
  size_t off = 0;
  unsigned short* mlx = (unsigned short*)(ws + off); off += (size_t)256 * 3 * 1024 * 64 * 2; // 100.7 MB
  unsigned short* hx  = (unsigned short*)(ws + off); off += (size_t)1028 * 16384 * 2;        //  33.7 MB
  float* cfin = (float*)(ws + off);                  off += (size_t)1024 * 64 * 4;
  unsigned int* sent = (unsigned int*)(ws + off);    off += (size_t)1028 * 512 * 4;          //   2.1 MB
  if (off > ws_size) return;  // insufficient workspace: bail cleanly

  hipMemsetAsync(sent, 0, (size_t)1028 * 512 * 4, stream);  // dataflow flags

  xproj_kernel<<<dim3(8, 3, 64), 512, 0, stream>>>(input, W_f, Wm_f, W_o, Wm_o, W_c, Wm_c, mlx);
  recur_kernel<<<128, 256, 0, stream>>>(U_f, Um_f, U_o, Um_o, U_c, Um_c,
                                        b_f, b_o, b_c, mlx, hx, cfin, sent);
  histcast_kernel<<<16384, 128, 0, stream>>>(hx, (float*)d_out);
  finals_kernel<<<256, 256, 0, stream>>>(hx, cfin, (float*)d_out);
}

// Round 9
// 2162.125 us; speedup vs baseline: 2.4276x; 2.4276x over previous
//
#include <hip/hip_runtime.h>
#include <hip/hip_bf16.h>

// GatedLSTM: B=64, T=256, IN=512, H=1024. i-gate dead in reference -> dropped.
// Round 9 = Round 4 (proven correct, best perf) + ONE structural fix:
// the 32 A-fragment loads are issued via inline asm (global_load_dwordx4 x32,
// one vmcnt(0), sched_barrier) so the compiler cannot sink/serialize them.
// R4/R5/R6 evidence says this serialization (~6-8 MALL round trips instead
// of 1) is the dominant per-step cost.

typedef __attribute__((ext_vector_type(8))) short bfrag;   // 8 x bf16 (4 VGPR)
typedef __attribute__((ext_vector_type(4))) float f32x4;   // MFMA accumulator
typedef __attribute__((ext_vector_type(4))) unsigned int u32x4;

__device__ __forceinline__ unsigned short f2b(float v) {
  __hip_bfloat16 h = __float2bfloat16(v);
  union { __hip_bfloat16 h; unsigned short u; } c; c.h = h; return c.u;
}
__device__ __forceinline__ float b2f(unsigned short u) {
  union { unsigned int i; float f; } c; c.i = ((unsigned int)u) << 16; return c.f;
}
__device__ __forceinline__ float sigm(float x) { return 1.0f / (1.0f + __expf(-x)); }
__device__ __forceinline__ float tanh_f(float x) {
  float e = __expf(2.0f * x);
  return (e - 1.0f) / (e + 1.0f);
}
__device__ __forceinline__ bfrag asbfrag(u32x4 v) {
  union { u32x4 u; bfrag b; } c; c.u = v; return c.b;
}

// ---------------------------------------------------------------------------
// Phase 1: x-projections (unchanged, proven). mlx[t][g][j][b] bf16.
// ---------------------------------------------------------------------------
__global__ __launch_bounds__(512, 2) void xproj_kernel(
    const float* __restrict__ inp,
    const float* __restrict__ Wf, const float* __restrict__ Wmf,
    const float* __restrict__ Wo, const float* __restrict__ Wmo,
    const float* __restrict__ Wc, const float* __restrict__ Wmc,
    unsigned short* __restrict__ mlx)
{
  __shared__ unsigned short Al[256 * 128];
  __shared__ unsigned short Bl[256 * 128];

  const int tid = threadIdx.x;
  const int w = tid >> 6, l = tid & 63;
  const int c = l & 15, g4 = l >> 4;
  const int jc = blockIdx.x, gate = blockIdx.y, tq = blockIdx.z;
  const float* W  = (gate == 0) ? Wf  : (gate == 1) ? Wo  : Wc;
  const float* Wm = (gate == 0) ? Wmf : (gate == 1) ? Wmo : Wmc;
  const int j0 = jc * 128;

  f32x4 acc[2][16];
#pragma unroll
  for (int mi = 0; mi < 2; ++mi)
#pragma unroll
    for (int ni = 0; ni < 16; ++ni) acc[mi][ni] = (f32x4){0.f, 0.f, 0.f, 0.f};

  for (int kc = 0; kc < 4; ++kc) {
#pragma unroll
    for (int i = 0; i < 16; ++i) {
      int idx = tid + i * 512;
      int row = idx >> 5;
      int xl  = idx & 31;
      int b_ = row & 63, tl = row >> 6;
      const float4 va = *(const float4*)(inp + (size_t)(b_ * 256 + tq * 4 + tl) * 512 + kc * 128 + xl * 4);
      ushort4 pa;
      pa.x = f2b(va.x); pa.y = f2b(va.y); pa.z = f2b(va.z); pa.w = f2b(va.w);
      *(ushort4*)((char*)Al + ((row * 256 + xl * 8) ^ ((row & 7) << 4))) = pa;
      const float* src = (row < 128) ? (W + (size_t)(j0 + row) * 512)
                                     : (Wm + (size_t)(j0 + row - 128) * 512);
      const float4 vb = *(const float4*)(src + kc * 128 + xl * 4);
      ushort4 pb;
      pb.x = f2b(vb.x); pb.y = f2b(vb.y); pb.z = f2b(vb.z); pb.w = f2b(vb.w);
      *(ushort4*)((char*)Bl + ((row * 256 + xl * 8) ^ ((row & 7) << 4))) = pb;
    }
    __syncthreads();
#pragma unroll
    for (int ks = 0; ks < 4; ++ks) {
      const int koff = (ks * 32 + g4 * 8) * 2;
      bfrag af[2];
#pragma unroll
      for (int mi = 0; mi < 2; ++mi) {
        int row = w * 32 + mi * 16 + c;
        af[mi] = *(const bfrag*)((const char*)Al + ((row * 256 + koff) ^ ((row & 7) << 4)));
      }
#pragma unroll
      for (int ni = 0; ni < 16; ++ni) {
        int n = ni * 16 + c;
        bfrag bf = *(const bfrag*)((const char*)Bl + ((n * 256 + koff) ^ ((n & 7) << 4)));
#pragma unroll
        for (int mi = 0; mi < 2; ++mi)
          acc[mi][ni] = __builtin_amdgcn_mfma_f32_16x16x32_bf16(af[mi], bf, acc[mi][ni], 0, 0, 0);
      }
    }
    __syncthreads();
  }
#pragma unroll
  for (int mi = 0; mi < 2; ++mi) {
#pragma unroll
    for (int ni = 0; ni < 8; ++ni) {
      f32x4 xw = acc[mi][ni];
      f32x4 xm = acc[mi][ni + 8];
      ushort4 st;
      st.x = f2b(xw[0] * sigm(xm[0]));
      st.y = f2b(xw[1] * sigm(xm[1]));
      st.z = f2b(xw[2] * sigm(xm[2]));
      st.w = f2b(xw[3] * sigm(xm[3]));
      int row = w * 32 + mi * 16 + g4 * 4;
      int tl = row >> 6, b_ = row & 63;
      int j = j0 + ni * 16 + c;
      size_t addr = ((size_t)((tq * 4 + tl) * 3 + gate) * 1024 + j) * 64 + b_;
      *(ushort4*)(mlx + addr) = st;
    }
  }
}

// ---------------------------------------------------------------------------
// Phase 2: persistent recurrent kernel (R4 structure + asm flat A-loads).
// 128 blocks x 256 threads, 1 block/CU (104 KB LDS). Block owns h-cols
// j0=8*bid..+8. hx chunk layout: hx[t][kb][b][8] bf16 (kb = block id).
// Per step per wave:
//   mlx issue -> sentinel poll (32 producers x 4 waves, 8B agent loads) ->
//   32x global_load_dwordx4 via asm (FLAT, one round trip) -> vmcnt(0) ->
//   sched_barrier -> 96 MFMAs -> prep ds_write (dbuf) -> one barrier ->
//   reduce+gates -> packed h dword agent-store -> vmcnt(0) -> sentinel.
// ---------------------------------------------------------------------------
__global__ __launch_bounds__(256, 1) void recur_kernel(
    const float* __restrict__ Uf, const float* __restrict__ Umf,
    const float* __restrict__ Uo, const float* __restrict__ Umo,
    const float* __restrict__ Uc, const float* __restrict__ Umc,
    const float* __restrict__ bfp, const float* __restrict__ bop,
    const float* __restrict__ bcp,
    const unsigned short* __restrict__ mlx,  // [256][3][1024][64] bf16
    unsigned short* __restrict__ hx,         // [257][128][64][8] bf16
    float* __restrict__ cfin,                // [1024][64] f32
    unsigned int* __restrict__ sent)         // [257][128][4]
{
  __shared__ float prep[2][4 * 48 * 68];     // 2 x 52 KB partials [w][col][row]

  // One-time L1+L2 invalidate: discards poison-epoch / cross-replay lines.
  __builtin_amdgcn_fence(__ATOMIC_ACQUIRE, "agent");

  const int tid = threadIdx.x;
  const int bid = blockIdx.x;
  const int w = tid >> 6, l = tid & 63;
  const int c = l & 15, g4 = l >> 4;
  const int j0 = bid * 8;

  // ---- one-time U stage into registers: Breg[nt][ks] -------------------
  bfrag Breg[3][8];
#pragma unroll
  for (int nt = 0; nt < 3; ++nt) {
    const int n = nt * 16 + c;          // 0..47
    const int mi6 = n >> 3;             // 0..5 (ternary chain: no scratch)
    const float* src = (mi6 == 0) ? Uf : (mi6 == 1) ? Umf : (mi6 == 2) ? Uo
                     : (mi6 == 3) ? Umo : (mi6 == 4) ? Uc : Umc;
    src += (size_t)(j0 + (n & 7)) * 1024;
#pragma unroll
    for (int ks = 0; ks < 8; ++ks) {
      const int k = w * 256 + ks * 32 + g4 * 8;
      const float4 v0 = *(const float4*)(src + k);
      const float4 v1 = *(const float4*)(src + k + 4);
      bfrag b;
      b[0] = (short)f2b(v0.x); b[1] = (short)f2b(v0.y);
      b[2] = (short)f2b(v0.z); b[3] = (short)f2b(v0.w);
      b[4] = (short)f2b(v1.x); b[5] = (short)f2b(v1.y);
      b[6] = (short)f2b(v1.z); b[7] = (short)f2b(v1.w);
      Breg[nt][ks] = b;
    }
  }

  const int bb = l;               // elementwise: b = lane, cols cl0 = 2w
  const int cl0 = w * 2;
  float bias[2][3], cr[2] = {0.f, 0.f};
#pragma unroll
  for (int q = 0; q < 2; ++q) {
    bias[q][0] = bfp[j0 + cl0 + q];
    bias[q][1] = bop[j0 + cl0 + q];
    bias[q][2] = bcp[j0 + cl0 + q];
  }

  for (int t = 0; t < 256; ++t) {
    // mlx for THIS step: issue first; HBM latency hides under the poll wait
    float mfv[2], mov[2], mcv[2];
    {
      size_t mb = (size_t)t * 3 * 65536 + (size_t)(j0 + cl0) * 64 + bb;
#pragma unroll
      for (int q = 0; q < 2; ++q) {
        mfv[q] = b2f(mlx[mb + q * 64]);
        mov[q] = b2f(mlx[mb + 65536 + q * 64]);
        mcv[q] = b2f(mlx[mb + 2 * 65536 + q * 64]);
      }
    }

    // ---- per-wave sentinel poll: producers 32w..32w+31, all 4 waves ----
    if (t > 0) {
      const unsigned long long* sp =
          (const unsigned long long*)(sent + (size_t)t * 512 + w * 128 + 2 * l);
      while (true) {
        unsigned long long v = __hip_atomic_load(sp, __ATOMIC_RELAXED, __HIP_MEMORY_SCOPE_AGENT);
        if (__all(v == 0x0000000100000001ULL)) break;
      }
      __builtin_amdgcn_sched_barrier(0);
      asm volatile("" ::: "memory");   // keep h loads below the poll
    }

    // ---- FLAT-issue ALL 32 A-fragment loads via asm (1 round trip) -----
    // lane base: chunk kb0 = w*32 + g4, row c; ks stride = 4 chunks = 4096B,
    // mi stride = 16 rows = 256B.
    u32x4 af[8][4];
    {
      const char* hb = (const char*)hx +
          ((((size_t)t * 128 + w * 32 + g4) * 64 + c) * 16);
#define LD4(KS) do {                                                           \
      const char* p_ = hb + (KS) * 4096;                                       \
      asm volatile("global_load_dwordx4 %0, %4, off\n\t"                       \
                   "global_load_dwordx4 %1, %4, off offset:256\n\t"            \
                   "global_load_dwordx4 %2, %4, off offset:512\n\t"            \
                   "global_load_dwordx4 %3, %4, off offset:768"                \
                   : "=v"(af[KS][0]), "=v"(af[KS][1]),                         \
                     "=v"(af[KS][2]), "=v"(af[KS][3])                          \
                   : "v"(p_) : "memory"); } while (0)
      LD4(0); LD4(1); LD4(2); LD4(3); LD4(4); LD4(5); LD4(6); LD4(7);
#undef LD4
      asm volatile("s_waitcnt vmcnt(0)" ::: "memory");
      __builtin_amdgcn_sched_barrier(0);
    }

    f32x4 acc[4][3];
#pragma unroll
    for (int mi = 0; mi < 4; ++mi)
#pragma unroll
      for (int nt = 0; nt < 3; ++nt) acc[mi][nt] = (f32x4){0.f, 0.f, 0.f, 0.f};

#pragma unroll
    for (int ks = 0; ks < 8; ++ks) {
#pragma unroll
      for (int mi = 0; mi < 4; ++mi) {
        const bfrag a = asbfrag(af[ks][mi]);
#pragma unroll
        for (int nt = 0; nt < 3; ++nt)
          acc[mi][nt] = __builtin_amdgcn_mfma_f32_16x16x32_bf16(a, Breg[nt][ks], acc[mi][nt], 0, 0, 0);
      }
    }

    float* pp = prep[t & 1];
#pragma unroll
    for (int mi = 0; mi < 4; ++mi)
#pragma unroll
      for (int nt = 0; nt < 3; ++nt) {
        int col = nt * 16 + c;
        *(f32x4*)&pp[(w * 48 + col) * 68 + mi * 16 + g4 * 4] = acc[mi][nt];
      }
    __syncthreads();   // the ONLY per-step barrier (prep double-buffered)

    unsigned int pack = 0;
#pragma unroll
    for (int q = 0; q < 2; ++q) {
      const int cl = cl0 + q;
      float s[6];
#pragma unroll
      for (int m = 0; m < 6; ++m) {
        const int col = m * 8 + cl;
        s[m] = pp[col * 68 + bb] + pp[(48 + col) * 68 + bb] +
               pp[(96 + col) * 68 + bb] + pp[(144 + col) * 68 + bb];
      }
      float fg = sigm(mfv[q] + sigm(s[1]) * s[0] + bias[q][0]);
      float og = sigm(mov[q] + sigm(s[3]) * s[2] + bias[q][1]);
      float cd = tanh_f(mcv[q] + sigm(s[5]) * s[4] + bias[q][2]);
      cr[q] = fg * cr[q] + cd;
      float hv = og * cr[q];
      pack |= (unsigned int)f2b(hv) << (16 * q);
      if (t == 255) cfin[(size_t)(j0 + cl) * 64 + bb] = cr[q];
    }
    // h dword -> unique chunk hx[t+1][bid][bb][cl0..+1] (agent write-through)
    __hip_atomic_store(
        (unsigned int*)(hx + ((((size_t)(t + 1) * 128 + bid) * 64 + bb) * 8 + cl0)),
        pack, __ATOMIC_RELAXED, __HIP_MEMORY_SCOPE_AGENT);

    // per-WAVE drain: this wave's h stores acked at MALL, then its sentinel
    asm volatile("s_waitcnt vmcnt(0)" ::: "memory");
    if (l == 0)
      __hip_atomic_store(&sent[(size_t)(t + 1) * 512 + bid * 4 + w], 1u,
                         __ATOMIC_RELAXED, __HIP_MEMORY_SCOPE_AGENT);
  }
}

// ---------------------------------------------------------------------------
// Phase 3: hx chunks -> out [b][t][j] f32 (streaming cast)
// ---------------------------------------------------------------------------
__global__ __launch_bounds__(128) void histcast_kernel(
    const unsigned short* __restrict__ hx, float* __restrict__ out)
{
  const int b = blockIdx.x >> 8, t = blockIdx.x & 255;
  const int j = threadIdx.x * 8;
  const unsigned short* src = hx + (((size_t)(t + 1) * 128 + (j >> 3)) * 64 + b) * 8;
  float* dst = out + ((size_t)b * 256 + t) * 1024 + j;
  ushort4 v0 = *(const ushort4*)(src);
  ushort4 v1 = *(const ushort4*)(src + 4);
  float4 o0, o1;
  o0.x = b2f(v0.x); o0.y = b2f(v0.y); o0.z = b2f(v0.z); o0.w = b2f(v0.w);
  o1.x = b2f(v1.x); o1.y = b2f(v1.y); o1.z = b2f(v1.z); o1.w = b2f(v1.w);
  *(float4*)(dst) = o0;
  *(float4*)(dst + 4) = o1;
}

__global__ __launch_bounds__(256) void finals_kernel(
    const unsigned short* __restrict__ hx, const float* __restrict__ cfin,
    float* __restrict__ out)
{
  int tid = blockIdx.x * 256 + threadIdx.x;  // 0..65535 = b*1024 + j
  int b = tid >> 10, j = tid & 1023;
  out[16777216 + tid]         = b2f(hx[(((size_t)256 * 128 + (j >> 3)) * 64 + b) * 8 + (j & 7)]);
  out[16777216 + 65536 + tid] = cfin[(size_t)j * 64 + b];
}

// ---------------------------------------------------------------------------
extern "C" void kernel_launch(void* const* d_in, const int* in_sizes, int n_in,
                              void* d_out, int out_size, void* d_ws, size_t ws_size,
                              hipStream_t stream)
{
  const float* input = (const float*)d_in[0];
  const float* W_f  = (const float*)d_in[1];
  const float* Wm_f = (const float*)d_in[2];
  const float* U_f  = (const float*)d_in[3];
  const float* Um_f = (const float*)d_in[4];
  const float* b_f  = (const float*)d_in[5];
  const float* W_o  = (const float*)d_in[11];
  const float* Wm_o = (const float*)d_in[12];
  const float* U_o  = (const float*)d_in[13];
  const float* Um_o = (const float*)d_in[14];
  const float* b_o  = (const float*)d_in[15];
  const float* W_c  = (const float*)d_in[16];
  const float* Wm_c = (const float*)d_in[17];
  const float* U_c  = (const float*)d_in[18];
  const float* Um_c = (const float*)d_in[19];
  const float* b_c  = (const float*)d_in[20];

  char* ws = (char*)d_ws;
  size_t off = 0;
  unsigned short* mlx = (unsigned short*)(ws + off); off += (size_t)256 * 3 * 1024 * 64 * 2; // 100.7 MB
  unsigned short* hx  = (unsigned short*)(ws + off); off += (size_t)257 * 128 * 64 * 8 * 2;  //  33.7 MB
  float* cfin = (float*)(ws + off);                  off += (size_t)1024 * 64 * 4;
  unsigned int* sent = (unsigned int*)(ws + off);    off += (size_t)257 * 512 * 4;           // 526 KB
  if (off > ws_size) return;  // insufficient workspace: bail cleanly

  hipMemsetAsync(hx, 0, 131072, stream);                  // h0 = 0 (chunk step 0)
  hipMemsetAsync(sent, 0, (size_t)257 * 512 * 4, stream); // sentinels

  xproj_kernel<<<dim3(8, 3, 64), 512, 0, stream>>>(input, W_f, Wm_f, W_o, Wm_o, W_c, Wm_c, mlx);
  recur_kernel<<<128, 256, 0, stream>>>(U_f, Um_f, U_o, Um_o, U_c, Um_c,
                                        b_f, b_o, b_c, mlx, hx, cfin, sent);
  histcast_kernel<<<16384, 128, 0, stream>>>(hx, (float*)d_out);
  finals_kernel<<<256, 256, 0, stream>>>(hx, cfin, (float*)d_out);
}